// Round 10
// baseline (273.442 us; speedup 1.0000x reference)
//
#include <hip/hip_runtime.h>
#include <cstdint>
#include <cstddef>

#define M_TOT 16384   // B*S = 4*4096
#define K_DIM 2048    // H
#define N_HALF 1024   // H/2
#define NT 32         // K tiles of BK=64
#define L2T 0.012976281620653759f  // log2(10000)/1024

typedef short bf16x8 __attribute__((ext_vector_type(8)));
typedef float f32x4 __attribute__((ext_vector_type(4)));
typedef unsigned short u16x4 __attribute__((ext_vector_type(4)));

__device__ __forceinline__ unsigned short f2bf(float f) {
    unsigned int u = __builtin_bit_cast(unsigned int, f);
    u += 0x7fffu + ((u >> 16) & 1u);   // RNE (no NaN inputs)
    return (unsigned short)(u >> 16);
}

// pack two f32 -> one dword of two bf16 (RNE), ~6 VALU via add3/and_or
__device__ __forceinline__ unsigned int pk2(float fa, float fb) {
    unsigned int ua = __builtin_bit_cast(unsigned int, fa);
    unsigned int ub = __builtin_bit_cast(unsigned int, fb);
    ua += 0x7fffu + ((ua >> 16) & 1u);
    ub += 0x7fffu + ((ub >> 16) & 1u);
    return (ua >> 16) | (ub & 0xffff0000u);
}

// W-only fp32 -> bf16 convert (x conversion is fused into the GEMM).
__global__ __launch_bounds__(256) void cvt_f32_bf16(const float4* __restrict__ in,
                                                    u16x4* __restrict__ out, int n4) {
    int idx = blockIdx.x * 256 + threadIdx.x;
    int stride = gridDim.x * 256;
    for (int i = idx; i < n4; i += stride) {
        float4 v = in[i];
        u16x4 o;
        o.x = f2bf(v.x); o.y = f2bf(v.y); o.z = f2bf(v.z); o.w = f2bf(v.w);
        out[i] = o;
    }
}

#define GLD16(g, l) __builtin_amdgcn_global_load_lds( \
    (const __attribute__((address_space(1))) void*)(g), \
    (__attribute__((address_space(3))) void*)(l), 16, 0, 0)

#define MFMA16x16(a, b, c) __builtin_amdgcn_mfma_f32_16x16x32_bf16((a), (b), (c), 0, 0, 0)
#define VMCNT0 asm volatile("s_waitcnt vmcnt(0)" ::: "memory")
#define VMCNT2 asm volatile("s_waitcnt vmcnt(2)" ::: "memory")
#define VMCNT4 asm volatile("s_waitcnt vmcnt(4)" ::: "memory")
#define VMCNT6 asm volatile("s_waitcnt vmcnt(6)" ::: "memory")
#define LGK0   asm volatile("s_waitcnt lgkmcnt(0)" ::: "memory")
#define LGK8   asm volatile("s_waitcnt lgkmcnt(8)" ::: "memory")
#define BAR    __builtin_amdgcn_s_barrier()
#define SCHED0 __builtin_amdgcn_sched_barrier(0)

// R8 skeleton + FUSED x fp32->bf16 conversion in the A-staging path.
// A: global f32 -> regs (float4 x4) -> pk2 cvt -> ds_write_b128 (T14 split:
// load issued 1 phase before cvt+write). B: global_load_lds DMA as before.
// vmcnt ledger (per tile): ph0 issues A0L*4+B0S*2, ph1 issues A1L*4+B1S*2;
// waits: ph0 vmcnt(6) [drains B1S(t)], ph1 vmcnt(2) [drains A0L],
// ph3 vmcnt(2) [drains A1L+B0S]. B frags are phase-local (re-read at ph2/ph3)
// to keep peak VGPR ~R8 level -- spills would corrupt the counted ledger.
__global__ __launch_bounds__(512, 2)
void gemm_rope(const float* __restrict__ Xf,
               const unsigned short* __restrict__ Wb,
               const float* __restrict__ bias,
               float* __restrict__ out)
{
    __shared__ __align__(16) unsigned short As[2][256][64];  // 64 KiB
    __shared__ __align__(16) unsigned short Bs[2][256][64];  // 64 KiB

    const int tid  = threadIdx.x;
    const int lane = tid & 63;
    const int wave = tid >> 6;
    const int wr = wave >> 2;   // 0..1  (row half)
    const int wc = wave & 3;    // 0..3  (col quarter)
    const int fr = lane & 15;
    const int hi = lane >> 4;   // 0..3

    // XCD-aware swizzle (grid=512, 512%8==0 -> bijective)
    const int bid = blockIdx.x;
    const int swz = (bid & 7) * 64 + (bid >> 3);
    const int nb = swz & 7;     // 8 col-pair blocks of 128
    const int mb = swz >> 3;    // 64 row blocks of 256
    const int m0 = mb * 256;
    const int c0 = nb * 128;

    // ---- staging address precompute (linear LDS dst, swizzled global src) ----
    const float* aSrcF[2][2];
    const unsigned short* bSrc[2][2];
    int aDst[2][2], bDst[2][2];
    #pragma unroll
    for (int l = 0; l < 2; ++l) {
        const int c = wave * 128 + l * 64 + lane;       // 16B-chunk index, 0..1023
        // A-unit(qi): rows {qi*64+[0,64)} U {128+qi*64+[0,64)}
        const int seg = c >> 9, within = c & 511;
        const int ris = within >> 3, cch = within & 7;
        const int kch = cch ^ (ris & 7);
        #pragma unroll
        for (int qi = 0; qi < 2; ++qi) {
            const int ldsrow = seg * 128 + qi * 64 + ris;
            aDst[qi][l] = ldsrow * 128 + cch * 16;
            const int grow = m0 + seg * 128 + qi * 64 + ris;
            aSrcF[qi][l] = Xf + (size_t)grow * K_DIM + kch * 8;
        }
        // B-unit(qj): rows qj*128+[0,128)
        const int rin = c >> 3, cchb = c & 7;
        const int kchb = cchb ^ (rin & 7);
        #pragma unroll
        for (int qj = 0; qj < 2; ++qj) {
            bDst[qj][l] = (qj * 128 + rin) * 128 + cchb * 16;
            const int wrow = qj * N_HALF + c0 + rin;
            bSrc[qj][l] = Wb + (size_t)wrow * K_DIM + kchb * 8;
        }
    }

    float4 fA[4];   // in-flight A unit (16 f32 = one 16KB-unit's per-lane share)

#define A_LOAD(q, kk) do { \
    fA[0] = *(const float4*)(aSrcF[q][0] + (size_t)(kk) * 64); \
    fA[1] = *(const float4*)(aSrcF[q][0] + (size_t)(kk) * 64 + 4); \
    fA[2] = *(const float4*)(aSrcF[q][1] + (size_t)(kk) * 64); \
    fA[3] = *(const float4*)(aSrcF[q][1] + (size_t)(kk) * 64 + 4); \
} while (0)
#define A_CVTWR(q, bb) do { \
    uint4 u0, u1; \
    u0.x = pk2(fA[0].x, fA[0].y); u0.y = pk2(fA[0].z, fA[0].w); \
    u0.z = pk2(fA[1].x, fA[1].y); u0.w = pk2(fA[1].z, fA[1].w); \
    u1.x = pk2(fA[2].x, fA[2].y); u1.y = pk2(fA[2].z, fA[2].w); \
    u1.z = pk2(fA[3].x, fA[3].y); u1.w = pk2(fA[3].z, fA[3].w); \
    *(uint4*)((char*)&As[bb][0][0] + aDst[q][0]) = u0; \
    *(uint4*)((char*)&As[bb][0][0] + aDst[q][1]) = u1; \
} while (0)
#define STAGE_B(q, bb, kk) do { \
    GLD16(bSrc[q][0] + (size_t)(kk) * 64, (char*)&Bs[bb][0][0] + bDst[q][0]); \
    GLD16(bSrc[q][1] + (size_t)(kk) * 64, (char*)&Bs[bb][0][0] + bDst[q][1]); \
} while (0)

    // frag-read swizzled k byte-offsets within a 128-B LDS row
    const int xorv = (fr & 7) << 4;
    const int koff0 = (hi * 16) ^ xorv;         // k-slice 0 (k=0..31)
    const int koff1 = (64 + hi * 16) ^ xorv;    // k-slice 1 (k=32..63)

#define READ_A(dst, bb, rb) do { _Pragma("unroll") \
    for (int i = 0; i < 4; ++i) { \
        dst[i][0] = *(const bf16x8*)((const char*)&As[bb][0][0] + ((rb) + i * 16 + fr) * 128 + koff0); \
        dst[i][1] = *(const bf16x8*)((const char*)&As[bb][0][0] + ((rb) + i * 16 + fr) * 128 + koff1); } } while (0)
#define READ_B(dst, bb, rb) do { _Pragma("unroll") \
    for (int j = 0; j < 2; ++j) { \
        dst[j][0] = *(const bf16x8*)((const char*)&Bs[bb][0][0] + ((rb) + j * 16 + fr) * 128 + koff0); \
        dst[j][1] = *(const bf16x8*)((const char*)&Bs[bb][0][0] + ((rb) + j * 16 + fr) * 128 + koff1); } } while (0)

    f32x4 acc[8][4];
    #pragma unroll
    for (int i = 0; i < 8; ++i)
        #pragma unroll
        for (int j = 0; j < 4; ++j)
            acc[i][j] = (f32x4){0.f, 0.f, 0.f, 0.f};

    bf16x8 aF[4][2], bF[2][2];

#define CLUSTER(r0, j0) do { \
    __builtin_amdgcn_s_setprio(1); \
    _Pragma("unroll") for (int i = 0; i < 4; ++i) \
      _Pragma("unroll") for (int j = 0; j < 2; ++j) { \
        acc[(r0) + i][(j0) + j] = MFMA16x16(aF[i][0], bF[j][0], acc[(r0) + i][(j0) + j]); \
        acc[(r0) + i][(j0) + j] = MFMA16x16(aF[i][1], bF[j][1], acc[(r0) + i][(j0) + j]); } \
    __builtin_amdgcn_s_setprio(0); } while (0)

    // ---- prologue: tile 0 -> buf 0 (A converted in-reg; simple full drains) ----
    A_LOAD(0, 0);
    STAGE_B(0, 0, 0);
    STAGE_B(1, 0, 0);
    VMCNT4;            // drains A0L(0); B stages may remain
    A_CVTWR(0, 0);
    A_LOAD(1, 0);
    VMCNT0;            // drains A1L(0) (+B stages; prologue-only full drain)
    A_CVTWR(1, 0);
    LGK0;              // own ds_writes drained before signaling
    BAR;

    for (int kt = 0; kt < NT; ++kt) {
        const int buf = kt & 1, nbuf = buf ^ 1;
        const int kp1 = (kt + 1 < NT) ? kt + 1 : NT - 1;  // clamped: harmless dead work at tail

        // ---- ph0: read A0+B0 [12]; issue A0L(kt+1), B0S(kt+1)->nbuf; Q00 ----
        {
            READ_A(aF, buf, wr * 128);
            READ_B(bF, buf, wc * 32);
            A_LOAD(0, kp1);
            STAGE_B(0, nbuf, kp1);
            VMCNT6;            // drains B1S(kt) before ph1 reads B1
            LGK8; BAR; LGK0; SCHED0;
            CLUSTER(0, 0);
        }
        // ---- ph1: read B1 [4]; cvt+write A0(kt+1); issue A1L(kt+1), B1S(kt+1); Q01 ----
        {
            READ_B(bF, buf, 128 + wc * 32);
            VMCNT2;            // drains A0L(kt+1)
            A_CVTWR(0, nbuf);
            A_LOAD(1, kp1);
            STAGE_B(1, nbuf, kp1);
            BAR; LGK0; SCHED0;
            CLUSTER(0, 2);
        }
        // ---- ph2: read A1 + re-read B0 [12]; Q10 ----
        {
            READ_A(aF, buf, wr * 128 + 64);
            READ_B(bF, buf, wc * 32);
            LGK8; BAR; LGK0; SCHED0;
            CLUSTER(4, 0);
        }
        // ---- ph3: re-read B1 [4]; cvt+write A1(kt+1); Q11 ----
        {
            READ_B(bF, buf, 128 + wc * 32);
            VMCNT2;            // drains A1L(kt+1) (+B0S(kt+1), safe early)
            A_CVTWR(1, nbuf);
            BAR; LGK0; SCHED0;
            CLUSTER(4, 2);
        }
    }
    VMCNT0;   // drain remaining B-stage DMA before epilogue

    // ---- epilogue: bias + RoPE + 2x, fp32 store ----
    // acc[i][cp] (cp=0,1): col ol = c0 + wc*32 + cp*16 + fr; acc[i][cp+2]: col ol+1024.
    // rows: m = m0 + wr*128 + i*16 + hi*4 + r  (block stays within one 4096-seq)
    const float fs0f = (float)((m0 + wr * 128 + hi * 4) & 4095);
    #pragma unroll
    for (int cp = 0; cp < 2; ++cp) {
        const int ol = c0 + wc * 32 + cp * 16 + fr;
        const float invf = exp2f(-L2T * (float)ol);
        const float bl = bias[ol], bh = bias[ol + N_HALF];
        float cs, sn, c1, s1, c13, s13;
        sincosf(fs0f * invf, &sn, &cs);      // base angle
        sincosf(invf, &s1, &c1);             // +1 row step
        sincosf(13.0f * invf, &s13, &c13);   // +13 (frag-boundary) step
        #pragma unroll
        for (int i = 0; i < 8; ++i) {
            #pragma unroll
            for (int r = 0; r < 4; ++r) {
                const int m = m0 + wr * 128 + i * 16 + hi * 4 + r;
                float* orow = out + (size_t)m * K_DIM + ol;
                const float ql = acc[i][cp][r] + bl;
                const float qh = acc[i][cp + 2][r] + bh;
                orow[0]      = 2.0f * (ql * cs - qh * sn);
                orow[N_HALF] = 2.0f * (qh * cs + ql * sn);
                float nc, ns;
                if (r < 3) { nc = cs * c1 - sn * s1;  ns = sn * c1 + cs * s1; }
                else       { nc = cs * c13 - sn * s13; ns = sn * c13 + cs * s13; }
                cs = nc; sn = ns;
            }
        }
    }
}

// Emergency fallback if workspace is too small: slow but correct fp32 path.
__global__ __launch_bounds__(256) void fallback_fused(const float* __restrict__ x,
                                                      const float* __restrict__ W,
                                                      const float* __restrict__ bias,
                                                      float* __restrict__ out)
{
    __shared__ float xs[K_DIM];
    const int m = blockIdx.x;
    const int tid = threadIdx.x;
    for (int k = tid; k < K_DIM; k += 256) xs[k] = x[(size_t)m * K_DIM + k];
    __syncthreads();
    const float fs = (float)(m & 4095);
    for (int ol = tid; ol < N_HALF; ol += 256) {
        const float* wl = W + (size_t)ol * K_DIM;
        const float* wh = W + (size_t)(ol + N_HALF) * K_DIM;
        float al = 0.f, ah = 0.f;
        for (int k = 0; k < K_DIM; ++k) { al += xs[k] * wl[k]; ah += xs[k] * wh[k]; }
        al += bias[ol]; ah += bias[ol + N_HALF];
        float sn, cs;
        sincosf(fs * exp2f(-L2T * (float)ol), &sn, &cs);
        out[(size_t)m * K_DIM + ol]          = 2.0f * (al * cs - ah * sn);
        out[(size_t)m * K_DIM + ol + N_HALF] = 2.0f * (ah * cs + al * sn);
    }
}

extern "C" void kernel_launch(void* const* d_in, const int* in_sizes, int n_in,
                              void* d_out, int out_size, void* d_ws, size_t ws_size,
                              hipStream_t stream)
{
    const float* x = (const float*)d_in[0];
    const float* W = (const float*)d_in[1];
    const float* b = (const float*)d_in[2];
    float* out = (float*)d_out;

    const size_t nw = (size_t)K_DIM * K_DIM;
    if (ws_size < nw * sizeof(unsigned short)) {
        fallback_fused<<<M_TOT, 256, 0, stream>>>(x, W, b, out);
        return;
    }
    unsigned short* wb = (unsigned short*)d_ws;
    cvt_f32_bf16<<<1024, 256, 0, stream>>>((const float4*)W, (u16x4*)wb, (int)(nw / 4));
    gemm_rope<<<(M_TOT / 256) * (N_HALF / 128), 512, 0, stream>>>(x, wb, b, out);
}

// Round 11
// 169.917 us; speedup vs baseline: 1.6093x; 1.6093x over previous
//
#include <hip/hip_runtime.h>
#include <cstdint>
#include <cstddef>

#define M_TOT 16384   // B*S = 4*4096
#define K_DIM 2048    // H
#define N_HALF 1024   // H/2
#define NT 32         // K tiles of BK=64
#define L2T 0.012976281620653759f  // log2(10000)/1024

typedef short bf16x8 __attribute__((ext_vector_type(8)));
typedef float f32x4 __attribute__((ext_vector_type(4)));
typedef unsigned short u16x4 __attribute__((ext_vector_type(4)));

__device__ __forceinline__ unsigned short f2bf(float f) {
    unsigned int u = __builtin_bit_cast(unsigned int, f);
    u += 0x7fffu + ((u >> 16) & 1u);   // RNE (no NaN inputs)
    return (unsigned short)(u >> 16);
}

// One launch converts both x and W (fp32 -> bf16), grid-stride.
__global__ __launch_bounds__(256) void cvt_f32_bf16_2(const float4* __restrict__ inA,
                                                      u16x4* __restrict__ outA, int n4A,
                                                      const float4* __restrict__ inB,
                                                      u16x4* __restrict__ outB, int n4B) {
    int idx = blockIdx.x * 256 + threadIdx.x;
    int stride = gridDim.x * 256;
    int tot = n4A + n4B;
    for (int i = idx; i < tot; i += stride) {
        const float4 v = (i < n4A) ? inA[i] : inB[i - n4A];
        u16x4 o;
        o.x = f2bf(v.x); o.y = f2bf(v.y); o.z = f2bf(v.z); o.w = f2bf(v.w);
        if (i < n4A) outA[i] = o; else outB[i - n4A] = o;
    }
}

#define GLD16(g, l) __builtin_amdgcn_global_load_lds( \
    (const __attribute__((address_space(1))) void*)(g), \
    (__attribute__((address_space(3))) void*)(l), 16, 0, 0)

#define MFMA16x16(a, b, c) __builtin_amdgcn_mfma_f32_16x16x32_bf16((a), (b), (c), 0, 0, 0)
#define VMCNT4 asm volatile("s_waitcnt vmcnt(4)" ::: "memory")
#define LGK0   asm volatile("s_waitcnt lgkmcnt(0)" ::: "memory")
#define LGK8   asm volatile("s_waitcnt lgkmcnt(8)" ::: "memory")
#define BAR    __builtin_amdgcn_s_barrier()
#define SCHED0 __builtin_amdgcn_sched_barrier(0)

// R8 (best measured: gemm 139.7us, total 170.0us).
// 256x(128low+128high) tile, BK=64, 512 thr (8 waves 2Mx4N), dbuf 128KiB LDS.
// Per phase: [ds_reads; stage 1 unit -> nbuf; vmcnt(4); (lgkm8 if 12 reads);
// s_barrier; lgkmcnt(0); setprio1; 16 MFMA; setprio0].
// Ledger: vmcnt(4) at each phase retires exactly the unit the NEXT phase's
// reads need (cross-wave visibility = own vmcnt before BAR + reads after BAR).
// Register budget: acc[8][4] = 128 AGPRs; frag/addr VGPRs fit in ~124 -> no
// spill. (Any extra read-ahead reg set exceeds the 256/wave unified budget
// at 2 waves/SIMD and spills -- measured R5/R7/R10.)
__global__ __launch_bounds__(512, 2)
void gemm_rope(const unsigned short* __restrict__ Xb,
               const unsigned short* __restrict__ Wb,
               const float* __restrict__ bias,
               float* __restrict__ out)
{
    __shared__ __align__(16) unsigned short As[2][256][64];  // 64 KiB
    __shared__ __align__(16) unsigned short Bs[2][256][64];  // 64 KiB

    const int tid  = threadIdx.x;
    const int lane = tid & 63;
    const int wave = tid >> 6;
    const int wr = wave >> 2;   // 0..1  (row half)
    const int wc = wave & 3;    // 0..3  (col quarter)
    const int fr = lane & 15;
    const int hi = lane >> 4;   // 0..3

    // XCD-aware swizzle (grid=512, 512%8==0 -> bijective)
    const int bid = blockIdx.x;
    const int swz = (bid & 7) * 64 + (bid >> 3);
    const int nb = swz & 7;     // 8 col-pair blocks of 128
    const int mb = swz >> 3;    // 64 row blocks of 256
    const int m0 = mb * 256;
    const int c0 = nb * 128;

    // ---- staging address precompute (linear LDS dst, swizzled global src) ----
    const unsigned short* aSrc[2][2];
    const unsigned short* bSrc[2][2];
    int aDst[2][2], bDst[2][2];
    #pragma unroll
    for (int l = 0; l < 2; ++l) {
        const int c = wave * 128 + l * 64 + lane;       // 16B-chunk index, 0..1023
        // A-unit(qi): rows {qi*64+[0,64)} U {128+qi*64+[0,64)}
        const int seg = c >> 9, within = c & 511;
        const int ris = within >> 3, cch = within & 7;
        const int kch = cch ^ (ris & 7);
        #pragma unroll
        for (int qi = 0; qi < 2; ++qi) {
            const int ldsrow = seg * 128 + qi * 64 + ris;
            aDst[qi][l] = ldsrow * 128 + cch * 16;
            const int grow = m0 + seg * 128 + qi * 64 + ris;
            aSrc[qi][l] = Xb + (size_t)grow * K_DIM + kch * 8;
        }
        // B-unit(qj): rows qj*128+[0,128)
        const int rin = c >> 3, cchb = c & 7;
        const int kchb = cchb ^ (rin & 7);
        #pragma unroll
        for (int qj = 0; qj < 2; ++qj) {
            bDst[qj][l] = (qj * 128 + rin) * 128 + cchb * 16;
            const int wrow = qj * N_HALF + c0 + rin;
            bSrc[qj][l] = Wb + (size_t)wrow * K_DIM + kchb * 8;
        }
    }

#define STAGE_A(q, bb, kk) do { \
    GLD16(aSrc[q][0] + (size_t)(kk) * 64, (char*)&As[bb][0][0] + aDst[q][0]); \
    GLD16(aSrc[q][1] + (size_t)(kk) * 64, (char*)&As[bb][0][0] + aDst[q][1]); \
} while (0)
#define STAGE_B(q, bb, kk) do { \
    GLD16(bSrc[q][0] + (size_t)(kk) * 64, (char*)&Bs[bb][0][0] + bDst[q][0]); \
    GLD16(bSrc[q][1] + (size_t)(kk) * 64, (char*)&Bs[bb][0][0] + bDst[q][1]); \
} while (0)

    // frag-read swizzled k byte-offsets within a 128-B LDS row
    const int xorv = (fr & 7) << 4;
    const int koff0 = (hi * 16) ^ xorv;         // k-slice 0 (k=0..31)
    const int koff1 = (64 + hi * 16) ^ xorv;    // k-slice 1 (k=32..63)

    f32x4 acc[8][4];
    #pragma unroll
    for (int i = 0; i < 8; ++i)
        #pragma unroll
        for (int j = 0; j < 4; ++j)
            acc[i][j] = (f32x4){0.f, 0.f, 0.f, 0.f};

    bf16x8 aF[4][2], b0F[2][2], b1F[2][2];

    // ---- prologue: tile 0 -> buf 0, unit order A0,B0,B1,A1 ----
    STAGE_A(0, 0, 0); STAGE_B(0, 0, 0); STAGE_B(1, 0, 0); STAGE_A(1, 0, 0);
    VMCNT4;   // A0,B0 of tile 0 landed (B1,A1 may be in flight)
    BAR;

    for (int kt = 0; kt < NT; ++kt) {
        const int buf = kt & 1, nbuf = buf ^ 1;
        const int kp1 = (kt + 1 < NT) ? kt + 1 : NT - 1;  // clamped: harmless dead stage at tail

        // ---- phase 0: read A0+B0 (12); stage A0(kt+1)->nbuf; MFMA acc[0..3][0..1] ----
        {
            const int rb = wr * 128 + fr;
            #pragma unroll
            for (int i = 0; i < 4; ++i) {
                aF[i][0] = *(const bf16x8*)((const char*)&As[buf][0][0] + (rb + i * 16) * 128 + koff0);
                aF[i][1] = *(const bf16x8*)((const char*)&As[buf][0][0] + (rb + i * 16) * 128 + koff1);
            }
            const int cb = wc * 32 + fr;
            #pragma unroll
            for (int j = 0; j < 2; ++j) {
                b0F[j][0] = *(const bf16x8*)((const char*)&Bs[buf][0][0] + (cb + j * 16) * 128 + koff0);
                b0F[j][1] = *(const bf16x8*)((const char*)&Bs[buf][0][0] + (cb + j * 16) * 128 + koff1);
            }
            STAGE_A(0, nbuf, kp1);
            VMCNT4; LGK8; BAR; LGK0; SCHED0;
            __builtin_amdgcn_s_setprio(1);
            #pragma unroll
            for (int i = 0; i < 4; ++i)
                #pragma unroll
                for (int j = 0; j < 2; ++j) {
                    acc[i][j] = MFMA16x16(aF[i][0], b0F[j][0], acc[i][j]);
                    acc[i][j] = MFMA16x16(aF[i][1], b0F[j][1], acc[i][j]);
                }
            __builtin_amdgcn_s_setprio(0);
        }
        // ---- phase 1: read B1 (4); stage B0(kt+1)->nbuf; MFMA acc[0..3][2..3] ----
        {
            const int cb = 128 + wc * 32 + fr;
            #pragma unroll
            for (int j = 0; j < 2; ++j) {
                b1F[j][0] = *(const bf16x8*)((const char*)&Bs[buf][0][0] + (cb + j * 16) * 128 + koff0);
                b1F[j][1] = *(const bf16x8*)((const char*)&Bs[buf][0][0] + (cb + j * 16) * 128 + koff1);
            }
            STAGE_B(0, nbuf, kp1);
            VMCNT4; BAR; LGK0; SCHED0;
            __builtin_amdgcn_s_setprio(1);
            #pragma unroll
            for (int i = 0; i < 4; ++i)
                #pragma unroll
                for (int j = 0; j < 2; ++j) {
                    acc[i][2 + j] = MFMA16x16(aF[i][0], b1F[j][0], acc[i][2 + j]);
                    acc[i][2 + j] = MFMA16x16(aF[i][1], b1F[j][1], acc[i][2 + j]);
                }
            __builtin_amdgcn_s_setprio(0);
        }
        // ---- phase 2: read A1 (8); stage B1(kt+1)->nbuf; MFMA acc[4..7][0..1] ----
        {
            const int rb = wr * 128 + 64 + fr;
            #pragma unroll
            for (int i = 0; i < 4; ++i) {
                aF[i][0] = *(const bf16x8*)((const char*)&As[buf][0][0] + (rb + i * 16) * 128 + koff0);
                aF[i][1] = *(const bf16x8*)((const char*)&As[buf][0][0] + (rb + i * 16) * 128 + koff1);
            }
            STAGE_B(1, nbuf, kp1);
            VMCNT4; BAR; LGK0; SCHED0;
            __builtin_amdgcn_s_setprio(1);
            #pragma unroll
            for (int i = 0; i < 4; ++i)
                #pragma unroll
                for (int j = 0; j < 2; ++j) {
                    acc[4 + i][j] = MFMA16x16(aF[i][0], b0F[j][0], acc[4 + i][j]);
                    acc[4 + i][j] = MFMA16x16(aF[i][1], b0F[j][1], acc[4 + i][j]);
                }
            __builtin_amdgcn_s_setprio(0);
        }
        // ---- phase 3: stage A1(kt+1)->nbuf; MFMA acc[4..7][2..3] ----
        {
            STAGE_A(1, nbuf, kp1);
            VMCNT4; BAR; SCHED0;
            __builtin_amdgcn_s_setprio(1);
            #pragma unroll
            for (int i = 0; i < 4; ++i)
                #pragma unroll
                for (int j = 0; j < 2; ++j) {
                    acc[4 + i][2 + j] = MFMA16x16(aF[i][0], b1F[j][0], acc[4 + i][2 + j]);
                    acc[4 + i][2 + j] = MFMA16x16(aF[i][1], b1F[j][1], acc[4 + i][2 + j]);
                }
            __builtin_amdgcn_s_setprio(0);
        }
    }
    asm volatile("s_waitcnt vmcnt(0)" ::: "memory");  // drain LDS-DMA before epilogue

    // ---- epilogue: bias + RoPE + 2x, fp32 store ----
    // acc[i][cp] (cp=0,1): col ol = c0 + wc*32 + cp*16 + fr; acc[i][cp+2]: col ol+1024.
    // rows: m = m0 + wr*128 + i*16 + hi*4 + r  (block stays within one 4096-seq)
    const float fs0f = (float)((m0 + wr * 128 + hi * 4) & 4095);
    #pragma unroll
    for (int cp = 0; cp < 2; ++cp) {
        const int ol = c0 + wc * 32 + cp * 16 + fr;
        const float invf = exp2f(-L2T * (float)ol);
        const float bl = bias[ol], bh = bias[ol + N_HALF];
        float cs, sn, c1, s1, c13, s13;
        sincosf(fs0f * invf, &sn, &cs);      // base angle
        sincosf(invf, &s1, &c1);             // +1 row step
        sincosf(13.0f * invf, &s13, &c13);   // +13 (frag-boundary) step
        #pragma unroll
        for (int i = 0; i < 8; ++i) {
            #pragma unroll
            for (int r = 0; r < 4; ++r) {
                const int m = m0 + wr * 128 + i * 16 + hi * 4 + r;
                float* orow = out + (size_t)m * K_DIM + ol;
                const float ql = acc[i][cp][r] + bl;
                const float qh = acc[i][cp + 2][r] + bh;
                orow[0]      = 2.0f * (ql * cs - qh * sn);
                orow[N_HALF] = 2.0f * (qh * cs + ql * sn);
                float nc, ns;
                if (r < 3) { nc = cs * c1 - sn * s1;  ns = sn * c1 + cs * s1; }
                else       { nc = cs * c13 - sn * s13; ns = sn * c13 + cs * s13; }
                cs = nc; sn = ns;
            }
        }
    }
}

// Emergency fallback if workspace is too small: slow but correct fp32 path.
__global__ __launch_bounds__(256) void fallback_fused(const float* __restrict__ x,
                                                      const float* __restrict__ W,
                                                      const float* __restrict__ bias,
                                                      float* __restrict__ out)
{
    __shared__ float xs[K_DIM];
    const int m = blockIdx.x;
    const int tid = threadIdx.x;
    for (int k = tid; k < K_DIM; k += 256) xs[k] = x[(size_t)m * K_DIM + k];
    __syncthreads();
    const float fs = (float)(m & 4095);
    for (int ol = tid; ol < N_HALF; ol += 256) {
        const float* wl = W + (size_t)ol * K_DIM;
        const float* wh = W + (size_t)(ol + N_HALF) * K_DIM;
        float al = 0.f, ah = 0.f;
        for (int k = 0; k < K_DIM; ++k) { al += xs[k] * wl[k]; ah += xs[k] * wh[k]; }
        al += bias[ol]; ah += bias[ol + N_HALF];
        float sn, cs;
        sincosf(fs * exp2f(-L2T * (float)ol), &sn, &cs);
        out[(size_t)m * K_DIM + ol]          = 2.0f * (al * cs - ah * sn);
        out[(size_t)m * K_DIM + ol + N_HALF] = 2.0f * (ah * cs + al * sn);
    }
}

extern "C" void kernel_launch(void* const* d_in, const int* in_sizes, int n_in,
                              void* d_out, int out_size, void* d_ws, size_t ws_size,
                              hipStream_t stream)
{
    const float* x = (const float*)d_in[0];
    const float* W = (const float*)d_in[1];
    const float* b = (const float*)d_in[2];
    float* out = (float*)d_out;

    const size_t nx = (size_t)M_TOT * K_DIM;
    const size_t nw = (size_t)K_DIM * K_DIM;
    const size_t need = (nx + nw) * sizeof(unsigned short);
    if (ws_size < need) {
        fallback_fused<<<M_TOT, 256, 0, stream>>>(x, W, b, out);
        return;
    }
    unsigned short* xb = (unsigned short*)d_ws;
    unsigned short* wb = xb + nx;
    cvt_f32_bf16_2<<<2048, 256, 0, stream>>>((const float4*)x, (u16x4*)xb, (int)(nx / 4),
                                             (const float4*)W, (u16x4*)wb, (int)(nw / 4));
    gemm_rope<<<(M_TOT / 256) * (N_HALF / 128), 512, 0, stream>>>(xb, wb, b, out);
}

// Round 12
// 169.299 us; speedup vs baseline: 1.6151x; 1.0037x over previous
//
#include <hip/hip_runtime.h>
#include <cstdint>
#include <cstddef>

#define M_TOT 16384   // B*S = 4*4096
#define K_DIM 2048    // H
#define N_HALF 1024   // H/2
#define NT 32         // K tiles of BK=64
#define L2T 0.012976281620653759f  // log2(10000)/1024

typedef short bf16x8 __attribute__((ext_vector_type(8)));
typedef float f32x4 __attribute__((ext_vector_type(4)));
typedef unsigned short u16x4 __attribute__((ext_vector_type(4)));

__device__ __forceinline__ unsigned short f2bf(float f) {
    unsigned int u = __builtin_bit_cast(unsigned int, f);
    u += 0x7fffu + ((u >> 16) & 1u);   // RNE (no NaN inputs)
    return (unsigned short)(u >> 16);
}

// One launch converts both x and W (fp32 -> bf16), grid-stride.
__global__ __launch_bounds__(256) void cvt_f32_bf16_2(const float4* __restrict__ inA,
                                                      u16x4* __restrict__ outA, int n4A,
                                                      const float4* __restrict__ inB,
                                                      u16x4* __restrict__ outB, int n4B) {
    int idx = blockIdx.x * 256 + threadIdx.x;
    int stride = gridDim.x * 256;
    int tot = n4A + n4B;
    for (int i = idx; i < tot; i += stride) {
        const float4 v = (i < n4A) ? inA[i] : inB[i - n4A];
        u16x4 o;
        o.x = f2bf(v.x); o.y = f2bf(v.y); o.z = f2bf(v.z); o.w = f2bf(v.w);
        if (i < n4A) outA[i] = o; else outB[i - n4A] = o;
    }
}

#define GLD16(g, l) __builtin_amdgcn_global_load_lds( \
    (const __attribute__((address_space(1))) void*)(g), \
    (__attribute__((address_space(3))) void*)(l), 16, 0, 0)

#define MFMA16x16(a, b, c) __builtin_amdgcn_mfma_f32_16x16x32_bf16((a), (b), (c), 0, 0, 0)
#define VMCNT4 asm volatile("s_waitcnt vmcnt(4)" ::: "memory")
#define BAR    __builtin_amdgcn_s_barrier()

// R8 structure with the FORCED LDS DRAINS REMOVED: reads are plain C++ LDS
// loads, so the compiler inserts minimal stepped lgkmcnt(N) before each
// dependent MFMA -- the blanket post-barrier lgkmcnt(0)+sched_barrier in R8
// serialized the whole phase's port drain ahead of the first MFMA. Reads are
// ordered B-first so availability matches MFMA consumption order. Manual
// waits kept ONLY where the compiler cannot infer them: vmcnt(4) for
// global_load_lds DMA (writes no registers) + barrier for cross-wave
// visibility. DMA-overwrite safety: each frag's last MFMA use (and its
// compiler-placed wait) is >=3 barrier-crossings before the kt+1 stage that
// overwrites its LDS region (all stages target nbuf only).
__global__ __launch_bounds__(512, 2)
void gemm_rope(const unsigned short* __restrict__ Xb,
               const unsigned short* __restrict__ Wb,
               const float* __restrict__ bias,
               float* __restrict__ out)
{
    __shared__ __align__(16) unsigned short As[2][256][64];  // 64 KiB
    __shared__ __align__(16) unsigned short Bs[2][256][64];  // 64 KiB

    const int tid  = threadIdx.x;
    const int lane = tid & 63;
    const int wave = tid >> 6;
    const int wr = wave >> 2;   // 0..1  (row half)
    const int wc = wave & 3;    // 0..3  (col quarter)
    const int fr = lane & 15;
    const int hi = lane >> 4;   // 0..3

    // XCD-aware swizzle (grid=512, 512%8==0 -> bijective)
    const int bid = blockIdx.x;
    const int swz = (bid & 7) * 64 + (bid >> 3);
    const int nb = swz & 7;     // 8 col-pair blocks of 128
    const int mb = swz >> 3;    // 64 row blocks of 256
    const int m0 = mb * 256;
    const int c0 = nb * 128;

    // ---- staging address precompute (linear LDS dst, swizzled global src) ----
    const unsigned short* aSrc[2][2];
    const unsigned short* bSrc[2][2];
    int aDst[2][2], bDst[2][2];
    #pragma unroll
    for (int l = 0; l < 2; ++l) {
        const int c = wave * 128 + l * 64 + lane;       // 16B-chunk index, 0..1023
        // A-unit(qi): rows {qi*64+[0,64)} U {128+qi*64+[0,64)}
        const int seg = c >> 9, within = c & 511;
        const int ris = within >> 3, cch = within & 7;
        const int kch = cch ^ (ris & 7);
        #pragma unroll
        for (int qi = 0; qi < 2; ++qi) {
            const int ldsrow = seg * 128 + qi * 64 + ris;
            aDst[qi][l] = ldsrow * 128 + cch * 16;
            const int grow = m0 + seg * 128 + qi * 64 + ris;
            aSrc[qi][l] = Xb + (size_t)grow * K_DIM + kch * 8;
        }
        // B-unit(qj): rows qj*128+[0,128)
        const int rin = c >> 3, cchb = c & 7;
        const int kchb = cchb ^ (rin & 7);
        #pragma unroll
        for (int qj = 0; qj < 2; ++qj) {
            bDst[qj][l] = (qj * 128 + rin) * 128 + cchb * 16;
            const int wrow = qj * N_HALF + c0 + rin;
            bSrc[qj][l] = Wb + (size_t)wrow * K_DIM + kchb * 8;
        }
    }

#define STAGE_A(q, bb, kk) do { \
    GLD16(aSrc[q][0] + (size_t)(kk) * 64, (char*)&As[bb][0][0] + aDst[q][0]); \
    GLD16(aSrc[q][1] + (size_t)(kk) * 64, (char*)&As[bb][0][0] + aDst[q][1]); \
} while (0)
#define STAGE_B(q, bb, kk) do { \
    GLD16(bSrc[q][0] + (size_t)(kk) * 64, (char*)&Bs[bb][0][0] + bDst[q][0]); \
    GLD16(bSrc[q][1] + (size_t)(kk) * 64, (char*)&Bs[bb][0][0] + bDst[q][1]); \
} while (0)

    // frag-read swizzled k byte-offsets within a 128-B LDS row
    const int xorv = (fr & 7) << 4;
    const int koff0 = (hi * 16) ^ xorv;         // k-slice 0 (k=0..31)
    const int koff1 = (64 + hi * 16) ^ xorv;    // k-slice 1 (k=32..63)

    f32x4 acc[8][4];
    #pragma unroll
    for (int i = 0; i < 8; ++i)
        #pragma unroll
        for (int j = 0; j < 4; ++j)
            acc[i][j] = (f32x4){0.f, 0.f, 0.f, 0.f};

    bf16x8 aF[4][2], b0F[2][2], b1F[2][2];

    // ---- prologue: tile 0 -> buf 0, unit order A0,B0,B1,A1 ----
    STAGE_A(0, 0, 0); STAGE_B(0, 0, 0); STAGE_B(1, 0, 0); STAGE_A(1, 0, 0);
    VMCNT4;   // A0,B0 of tile 0 landed (B1,A1 may be in flight)
    BAR;

    for (int kt = 0; kt < NT; ++kt) {
        const int buf = kt & 1, nbuf = buf ^ 1;
        const int kp1 = (kt + 1 < NT) ? kt + 1 : NT - 1;  // clamped: harmless dead stage at tail

        // ---- phase 0: read B0 then A0 (12); stage A0(kt+1)->nbuf; MFMA acc[0..3][0..1] ----
        {
            const int cb = wc * 32 + fr;
            #pragma unroll
            for (int j = 0; j < 2; ++j) {
                b0F[j][0] = *(const bf16x8*)((const char*)&Bs[buf][0][0] + (cb + j * 16) * 128 + koff0);
                b0F[j][1] = *(const bf16x8*)((const char*)&Bs[buf][0][0] + (cb + j * 16) * 128 + koff1);
            }
            const int rb = wr * 128 + fr;
            #pragma unroll
            for (int i = 0; i < 4; ++i) {
                aF[i][0] = *(const bf16x8*)((const char*)&As[buf][0][0] + (rb + i * 16) * 128 + koff0);
                aF[i][1] = *(const bf16x8*)((const char*)&As[buf][0][0] + (rb + i * 16) * 128 + koff1);
            }
            STAGE_A(0, nbuf, kp1);
            VMCNT4; BAR;
            __builtin_amdgcn_s_setprio(1);
            #pragma unroll
            for (int i = 0; i < 4; ++i)
                #pragma unroll
                for (int j = 0; j < 2; ++j) {
                    acc[i][j] = MFMA16x16(aF[i][0], b0F[j][0], acc[i][j]);
                    acc[i][j] = MFMA16x16(aF[i][1], b0F[j][1], acc[i][j]);
                }
            __builtin_amdgcn_s_setprio(0);
        }
        // ---- phase 1: read B1 (4); stage B0(kt+1)->nbuf; MFMA acc[0..3][2..3] ----
        {
            const int cb = 128 + wc * 32 + fr;
            #pragma unroll
            for (int j = 0; j < 2; ++j) {
                b1F[j][0] = *(const bf16x8*)((const char*)&Bs[buf][0][0] + (cb + j * 16) * 128 + koff0);
                b1F[j][1] = *(const bf16x8*)((const char*)&Bs[buf][0][0] + (cb + j * 16) * 128 + koff1);
            }
            STAGE_B(0, nbuf, kp1);
            VMCNT4; BAR;
            __builtin_amdgcn_s_setprio(1);
            #pragma unroll
            for (int i = 0; i < 4; ++i)
                #pragma unroll
                for (int j = 0; j < 2; ++j) {
                    acc[i][2 + j] = MFMA16x16(aF[i][0], b1F[j][0], acc[i][2 + j]);
                    acc[i][2 + j] = MFMA16x16(aF[i][1], b1F[j][1], acc[i][2 + j]);
                }
            __builtin_amdgcn_s_setprio(0);
        }
        // ---- phase 2: read A1 (8, reuses b0F in regs); stage B1(kt+1)->nbuf; MFMA acc[4..7][0..1] ----
        {
            const int rb = wr * 128 + 64 + fr;
            #pragma unroll
            for (int i = 0; i < 4; ++i) {
                aF[i][0] = *(const bf16x8*)((const char*)&As[buf][0][0] + (rb + i * 16) * 128 + koff0);
                aF[i][1] = *(const bf16x8*)((const char*)&As[buf][0][0] + (rb + i * 16) * 128 + koff1);
            }
            STAGE_B(1, nbuf, kp1);
            VMCNT4; BAR;
            __builtin_amdgcn_s_setprio(1);
            #pragma unroll
            for (int i = 0; i < 4; ++i)
                #pragma unroll
                for (int j = 0; j < 2; ++j) {
                    acc[4 + i][j] = MFMA16x16(aF[i][0], b0F[j][0], acc[4 + i][j]);
                    acc[4 + i][j] = MFMA16x16(aF[i][1], b0F[j][1], acc[4 + i][j]);
                }
            __builtin_amdgcn_s_setprio(0);
        }
        // ---- phase 3: stage A1(kt+1)->nbuf; MFMA acc[4..7][2..3] (all frags in regs) ----
        {
            STAGE_A(1, nbuf, kp1);
            VMCNT4; BAR;
            __builtin_amdgcn_s_setprio(1);
            #pragma unroll
            for (int i = 0; i < 4; ++i)
                #pragma unroll
                for (int j = 0; j < 2; ++j) {
                    acc[4 + i][2 + j] = MFMA16x16(aF[i][0], b1F[j][0], acc[4 + i][2 + j]);
                    acc[4 + i][2 + j] = MFMA16x16(aF[i][1], b1F[j][1], acc[4 + i][2 + j]);
                }
            __builtin_amdgcn_s_setprio(0);
        }
    }
    asm volatile("s_waitcnt vmcnt(0)" ::: "memory");  // drain LDS-DMA before epilogue

    // ---- epilogue: bias + RoPE + 2x, fp32 store ----
    // acc[i][cp] (cp=0,1): col ol = c0 + wc*32 + cp*16 + fr; acc[i][cp+2]: col ol+1024.
    // rows: m = m0 + wr*128 + i*16 + hi*4 + r  (block stays within one 4096-seq)
    const float fs0f = (float)((m0 + wr * 128 + hi * 4) & 4095);
    #pragma unroll
    for (int cp = 0; cp < 2; ++cp) {
        const int ol = c0 + wc * 32 + cp * 16 + fr;
        const float invf = exp2f(-L2T * (float)ol);
        const float bl = bias[ol], bh = bias[ol + N_HALF];
        float cs, sn, c1, s1, c13, s13;
        sincosf(fs0f * invf, &sn, &cs);      // base angle
        sincosf(invf, &s1, &c1);             // +1 row step
        sincosf(13.0f * invf, &s13, &c13);   // +13 (frag-boundary) step
        #pragma unroll
        for (int i = 0; i < 8; ++i) {
            #pragma unroll
            for (int r = 0; r < 4; ++r) {
                const int m = m0 + wr * 128 + i * 16 + hi * 4 + r;
                float* orow = out + (size_t)m * K_DIM + ol;
                const float ql = acc[i][cp][r] + bl;
                const float qh = acc[i][cp + 2][r] + bh;
                orow[0]      = 2.0f * (ql * cs - qh * sn);
                orow[N_HALF] = 2.0f * (qh * cs + ql * sn);
                float nc, ns;
                if (r < 3) { nc = cs * c1 - sn * s1;  ns = sn * c1 + cs * s1; }
                else       { nc = cs * c13 - sn * s13; ns = sn * c13 + cs * s13; }
                cs = nc; sn = ns;
            }
        }
    }
}

// Emergency fallback if workspace is too small: slow but correct fp32 path.
__global__ __launch_bounds__(256) void fallback_fused(const float* __restrict__ x,
                                                      const float* __restrict__ W,
                                                      const float* __restrict__ bias,
                                                      float* __restrict__ out)
{
    __shared__ float xs[K_DIM];
    const int m = blockIdx.x;
    const int tid = threadIdx.x;
    for (int k = tid; k < K_DIM; k += 256) xs[k] = x[(size_t)m * K_DIM + k];
    __syncthreads();
    const float fs = (float)(m & 4095);
    for (int ol = tid; ol < N_HALF; ol += 256) {
        const float* wl = W + (size_t)ol * K_DIM;
        const float* wh = W + (size_t)(ol + N_HALF) * K_DIM;
        float al = 0.f, ah = 0.f;
        for (int k = 0; k < K_DIM; ++k) { al += xs[k] * wl[k]; ah += xs[k] * wh[k]; }
        al += bias[ol]; ah += bias[ol + N_HALF];
        float sn, cs;
        sincosf(fs * exp2f(-L2T * (float)ol), &sn, &cs);
        out[(size_t)m * K_DIM + ol]          = 2.0f * (al * cs - ah * sn);
        out[(size_t)m * K_DIM + ol + N_HALF] = 2.0f * (ah * cs + al * sn);
    }
}

extern "C" void kernel_launch(void* const* d_in, const int* in_sizes, int n_in,
                              void* d_out, int out_size, void* d_ws, size_t ws_size,
                              hipStream_t stream)
{
    const float* x = (const float*)d_in[0];
    const float* W = (const float*)d_in[1];
    const float* b = (const float*)d_in[2];
    float* out = (float*)d_out;

    const size_t nx = (size_t)M_TOT * K_DIM;
    const size_t nw = (size_t)K_DIM * K_DIM;
    const size_t need = (nx + nw) * sizeof(unsigned short);
    if (ws_size < need) {
        fallback_fused<<<M_TOT, 256, 0, stream>>>(x, W, b, out);
        return;
    }
    unsigned short* xb = (unsigned short*)d_ws;
    unsigned short* wb = xb + nx;
    cvt_f32_bf16_2<<<2048, 256, 0, stream>>>((const float4*)x, (u16x4*)xb, (int)(nx / 4),
                                             (const float4*)W, (u16x4*)wb, (int)(nw / 4));
    gemm_rope<<<(M_TOT / 256) * (N_HALF / 128), 512, 0, stream>>>(xb, wb, b, out);
}

// Round 14
// 168.109 us; speedup vs baseline: 1.6266x; 1.0071x over previous
//
#include <hip/hip_runtime.h>
#include <cstdint>
#include <cstddef>

#define M_TOT 16384   // B*S = 4*4096
#define K_DIM 2048    // H
#define N_HALF 1024   // H/2
#define NT 32         // K tiles of BK=64
#define L2T 0.012976281620653759f  // log2(10000)/1024

typedef short bf16x8 __attribute__((ext_vector_type(8)));
typedef float f32x4 __attribute__((ext_vector_type(4)));
typedef unsigned short u16x4 __attribute__((ext_vector_type(4)));

__device__ __forceinline__ unsigned short f2bf(float f) {
    unsigned int u = __builtin_bit_cast(unsigned int, f);
    u += 0x7fffu + ((u >> 16) & 1u);   // RNE (no NaN inputs)
    return (unsigned short)(u >> 16);
}

// One launch converts both x and W (fp32 -> bf16), grid-stride.
__global__ __launch_bounds__(256) void cvt_f32_bf16_2(const float4* __restrict__ inA,
                                                      u16x4* __restrict__ outA, int n4A,
                                                      const float4* __restrict__ inB,
                                                      u16x4* __restrict__ outB, int n4B) {
    int idx = blockIdx.x * 256 + threadIdx.x;
    int stride = gridDim.x * 256;
    int tot = n4A + n4B;
    for (int i = idx; i < tot; i += stride) {
        const float4 v = (i < n4A) ? inA[i] : inB[i - n4A];
        u16x4 o;
        o.x = f2bf(v.x); o.y = f2bf(v.y); o.z = f2bf(v.z); o.w = f2bf(v.w);
        if (i < n4A) outA[i] = o; else outB[i - n4A] = o;
    }
}

#define GLD16(g, l) __builtin_amdgcn_global_load_lds( \
    (const __attribute__((address_space(1))) void*)(g), \
    (__attribute__((address_space(3))) void*)(l), 16, 0, 0)

#define MFMA16x16(a, b, c) __builtin_amdgcn_mfma_f32_16x16x32_bf16((a), (b), (c), 0, 0, 0)
#define VMCNT2 asm volatile("s_waitcnt vmcnt(2)" ::: "memory")
#define VMCNT6 asm volatile("s_waitcnt vmcnt(6)" ::: "memory")
#define BAR    __builtin_amdgcn_s_barrier()

// 2-phase/K-tile schedule, CORRECTED ledger (R13's bug: reads preceded the
// wait that covered them; every read raced). Invariant: a unit is read only
// in an epoch after EVERY wave's own vmcnt retired it, then a barrier.
//  phA(kt): reads A0,B0,B1(kt)   [retired by phB(kt-1) vmcnt(2)+BAR]
//           stage A0,B0,B1(kt+1) -> nbuf   (6 loads; queue 2+6=8)
//           vmcnt(6) -> retires A1(kt)     [needed by phB(kt)]
//           BAR; 32 MFMA rows 0..3 x all cols
//  phB(kt): reads A1(kt)
//           stage A1(kt+1) -> nbuf         (2 loads; queue 6+2=8)
//           vmcnt(2) -> retires A0,B0,B1(kt+1) [needed by phA(kt+1)]
//           BAR; 32 MFMA rows 4..7 x all cols
// Stage split is FORCED by the >=2-phase overwrite rule: region's last reads
// in phase p -> overwriting DMA must issue after BAR(p+1). A0/B0/B1 last
// read phA(kt-1) -> stage at phA(kt) ok; A1 last read phB(kt-1) -> stage at
// phB(kt) ok. LDS reads are plain C++ (compiler emits stepped lgkmcnt before
// dependent MFMAs -- R12's proven +13us). Same registers as R12 (no spill).
__global__ __launch_bounds__(512, 2)
void gemm_rope(const unsigned short* __restrict__ Xb,
               const unsigned short* __restrict__ Wb,
               const float* __restrict__ bias,
               float* __restrict__ out)
{
    __shared__ __align__(16) unsigned short As[2][256][64];  // 64 KiB
    __shared__ __align__(16) unsigned short Bs[2][256][64];  // 64 KiB

    const int tid  = threadIdx.x;
    const int lane = tid & 63;
    const int wave = tid >> 6;
    const int wr = wave >> 2;   // 0..1  (row half)
    const int wc = wave & 3;    // 0..3  (col quarter)
    const int fr = lane & 15;
    const int hi = lane >> 4;   // 0..3

    // XCD-aware swizzle (grid=512, 512%8==0 -> bijective)
    const int bid = blockIdx.x;
    const int swz = (bid & 7) * 64 + (bid >> 3);
    const int nb = swz & 7;     // 8 col-pair blocks of 128
    const int mb = swz >> 3;    // 64 row blocks of 256
    const int m0 = mb * 256;
    const int c0 = nb * 128;

    // ---- staging address precompute (linear LDS dst, swizzled global src) ----
    const unsigned short* aSrc[2][2];
    const unsigned short* bSrc[2][2];
    int aDst[2][2], bDst[2][2];
    #pragma unroll
    for (int l = 0; l < 2; ++l) {
        const int c = wave * 128 + l * 64 + lane;       // 16B-chunk index, 0..1023
        // A-unit(qi): rows {qi*64+[0,64)} U {128+qi*64+[0,64)}
        const int seg = c >> 9, within = c & 511;
        const int ris = within >> 3, cch = within & 7;
        const int kch = cch ^ (ris & 7);
        #pragma unroll
        for (int qi = 0; qi < 2; ++qi) {
            const int ldsrow = seg * 128 + qi * 64 + ris;
            aDst[qi][l] = ldsrow * 128 + cch * 16;
            const int grow = m0 + seg * 128 + qi * 64 + ris;
            aSrc[qi][l] = Xb + (size_t)grow * K_DIM + kch * 8;
        }
        // B-unit(qj): rows qj*128+[0,128)
        const int rin = c >> 3, cchb = c & 7;
        const int kchb = cchb ^ (rin & 7);
        #pragma unroll
        for (int qj = 0; qj < 2; ++qj) {
            bDst[qj][l] = (qj * 128 + rin) * 128 + cchb * 16;
            const int wrow = qj * N_HALF + c0 + rin;
            bSrc[qj][l] = Wb + (size_t)wrow * K_DIM + kchb * 8;
        }
    }

#define STAGE_A(q, bb, kk) do { \
    GLD16(aSrc[q][0] + (size_t)(kk) * 64, (char*)&As[bb][0][0] + aDst[q][0]); \
    GLD16(aSrc[q][1] + (size_t)(kk) * 64, (char*)&As[bb][0][0] + aDst[q][1]); \
} while (0)
#define STAGE_B(q, bb, kk) do { \
    GLD16(bSrc[q][0] + (size_t)(kk) * 64, (char*)&Bs[bb][0][0] + bDst[q][0]); \
    GLD16(bSrc[q][1] + (size_t)(kk) * 64, (char*)&Bs[bb][0][0] + bDst[q][1]); \
} while (0)

    // frag-read swizzled k byte-offsets within a 128-B LDS row
    const int xorv = (fr & 7) << 4;
    const int koff0 = (hi * 16) ^ xorv;         // k-slice 0 (k=0..31)
    const int koff1 = (64 + hi * 16) ^ xorv;    // k-slice 1 (k=32..63)

    f32x4 acc[8][4];
    #pragma unroll
    for (int i = 0; i < 8; ++i)
        #pragma unroll
        for (int j = 0; j < 4; ++j)
            acc[i][j] = (f32x4){0.f, 0.f, 0.f, 0.f};

    bf16x8 aF[4][2], b0F[2][2], b1F[2][2];

    // ---- prologue: tile 0 -> buf 0, unit order A0,B0,B1,A1 ----
    STAGE_A(0, 0, 0); STAGE_B(0, 0, 0); STAGE_B(1, 0, 0); STAGE_A(1, 0, 0);
    VMCNT2;   // retires A0,B0,B1 of tile 0 (A1 may be in flight)
    BAR;

    for (int kt = 0; kt < NT; ++kt) {
        const int buf = kt & 1, nbuf = buf ^ 1;
        const int kp1 = (kt + 1 < NT) ? kt + 1 : NT - 1;  // clamped: harmless dead stage at tail

        // ---- phase A: read B0,A0,B1 (16); stage A0,B0,B1(kt+1)->nbuf; vmcnt(6); MFMA rows 0..3 ----
        {
            const int cb = wc * 32 + fr;
            #pragma unroll
            for (int j = 0; j < 2; ++j) {
                b0F[j][0] = *(const bf16x8*)((const char*)&Bs[buf][0][0] + (cb + j * 16) * 128 + koff0);
                b0F[j][1] = *(const bf16x8*)((const char*)&Bs[buf][0][0] + (cb + j * 16) * 128 + koff1);
            }
            const int rb = wr * 128 + fr;
            #pragma unroll
            for (int i = 0; i < 4; ++i) {
                aF[i][0] = *(const bf16x8*)((const char*)&As[buf][0][0] + (rb + i * 16) * 128 + koff0);
                aF[i][1] = *(const bf16x8*)((const char*)&As[buf][0][0] + (rb + i * 16) * 128 + koff1);
            }
            const int cb1 = 128 + wc * 32 + fr;
            #pragma unroll
            for (int j = 0; j < 2; ++j) {
                b1F[j][0] = *(const bf16x8*)((const char*)&Bs[buf][0][0] + (cb1 + j * 16) * 128 + koff0);
                b1F[j][1] = *(const bf16x8*)((const char*)&Bs[buf][0][0] + (cb1 + j * 16) * 128 + koff1);
            }
            STAGE_A(0, nbuf, kp1);
            STAGE_B(0, nbuf, kp1);
            STAGE_B(1, nbuf, kp1);
            VMCNT6;   // queue 2+6=8 -> retires A1(kt) for phase B
            BAR;
            __builtin_amdgcn_s_setprio(1);
            #pragma unroll
            for (int i = 0; i < 4; ++i)
                #pragma unroll
                for (int j = 0; j < 2; ++j) {
                    acc[i][j] = MFMA16x16(aF[i][0], b0F[j][0], acc[i][j]);
                    acc[i][j] = MFMA16x16(aF[i][1], b0F[j][1], acc[i][j]);
                }
            #pragma unroll
            for (int i = 0; i < 4; ++i)
                #pragma unroll
                for (int j = 0; j < 2; ++j) {
                    acc[i][2 + j] = MFMA16x16(aF[i][0], b1F[j][0], acc[i][2 + j]);
                    acc[i][2 + j] = MFMA16x16(aF[i][1], b1F[j][1], acc[i][2 + j]);
                }
            __builtin_amdgcn_s_setprio(0);
        }
        // ---- phase B: read A1 (8); stage A1(kt+1)->nbuf; vmcnt(2); MFMA rows 4..7 ----
        {
            const int rb = wr * 128 + 64 + fr;
            #pragma unroll
            for (int i = 0; i < 4; ++i) {
                aF[i][0] = *(const bf16x8*)((const char*)&As[buf][0][0] + (rb + i * 16) * 128 + koff0);
                aF[i][1] = *(const bf16x8*)((const char*)&As[buf][0][0] + (rb + i * 16) * 128 + koff1);
            }
            STAGE_A(1, nbuf, kp1);
            VMCNT2;   // queue 6+2=8 -> retires A0,B0,B1(kt+1) for next phase A
            BAR;
            __builtin_amdgcn_s_setprio(1);
            #pragma unroll
            for (int i = 0; i < 4; ++i)
                #pragma unroll
                for (int j = 0; j < 2; ++j) {
                    acc[4 + i][j] = MFMA16x16(aF[i][0], b0F[j][0], acc[4 + i][j]);
                    acc[4 + i][j] = MFMA16x16(aF[i][1], b0F[j][1], acc[4 + i][j]);
                }
            #pragma unroll
            for (int i = 0; i < 4; ++i)
                #pragma unroll
                for (int j = 0; j < 2; ++j) {
                    acc[4 + i][2 + j] = MFMA16x16(aF[i][0], b1F[j][0], acc[4 + i][2 + j]);
                    acc[4 + i][2 + j] = MFMA16x16(aF[i][1], b1F[j][1], acc[4 + i][2 + j]);
                }
            __builtin_amdgcn_s_setprio(0);
        }
    }
    asm volatile("s_waitcnt vmcnt(0)" ::: "memory");  // drain LDS-DMA before epilogue

    // ---- epilogue: bias + RoPE + 2x, fp32 store ----
    // acc[i][cp] (cp=0,1): col ol = c0 + wc*32 + cp*16 + fr; acc[i][cp+2]: col ol+1024.
    // rows: m = m0 + wr*128 + i*16 + hi*4 + r  (block stays within one 4096-seq)
    const float fs0f = (float)((m0 + wr * 128 + hi * 4) & 4095);
    #pragma unroll
    for (int cp = 0; cp < 2; ++cp) {
        const int ol = c0 + wc * 32 + cp * 16 + fr;
        const float invf = exp2f(-L2T * (float)ol);
        const float bl = bias[ol], bh = bias[ol + N_HALF];
        float cs, sn, c1, s1, c13, s13;
        sincosf(fs0f * invf, &sn, &cs);      // base angle
        sincosf(invf, &s1, &c1);             // +1 row step
        sincosf(13.0f * invf, &s13, &c13);   // +13 (frag-boundary) step
        #pragma unroll
        for (int i = 0; i < 8; ++i) {
            #pragma unroll
            for (int r = 0; r < 4; ++r) {
                const int m = m0 + wr * 128 + i * 16 + hi * 4 + r;
                float* orow = out + (size_t)m * K_DIM + ol;
                const float ql = acc[i][cp][r] + bl;
                const float qh = acc[i][cp + 2][r] + bh;
                orow[0]      = 2.0f * (ql * cs - qh * sn);
                orow[N_HALF] = 2.0f * (qh * cs + ql * sn);
                float nc, ns;
                if (r < 3) { nc = cs * c1 - sn * s1;  ns = sn * c1 + cs * s1; }
                else       { nc = cs * c13 - sn * s13; ns = sn * c13 + cs * s13; }
                cs = nc; sn = ns;
            }
        }
    }
}

// Emergency fallback if workspace is too small: slow but correct fp32 path.
__global__ __launch_bounds__(256) void fallback_fused(const float* __restrict__ x,
                                                      const float* __restrict__ W,
                                                      const float* __restrict__ bias,
                                                      float* __restrict__ out)
{
    __shared__ float xs[K_DIM];
    const int m = blockIdx.x;
    const int tid = threadIdx.x;
    for (int k = tid; k < K_DIM; k += 256) xs[k] = x[(size_t)m * K_DIM + k];
    __syncthreads();
    const float fs = (float)(m & 4095);
    for (int ol = tid; ol < N_HALF; ol += 256) {
        const float* wl = W + (size_t)ol * K_DIM;
        const float* wh = W + (size_t)(ol + N_HALF) * K_DIM;
        float al = 0.f, ah = 0.f;
        for (int k = 0; k < K_DIM; ++k) { al += xs[k] * wl[k]; ah += xs[k] * wh[k]; }
        al += bias[ol]; ah += bias[ol + N_HALF];
        float sn, cs;
        sincosf(fs * exp2f(-L2T * (float)ol), &sn, &cs);
        out[(size_t)m * K_DIM + ol]          = 2.0f * (al * cs - ah * sn);
        out[(size_t)m * K_DIM + ol + N_HALF] = 2.0f * (ah * cs + al * sn);
    }
}

extern "C" void kernel_launch(void* const* d_in, const int* in_sizes, int n_in,
                              void* d_out, int out_size, void* d_ws, size_t ws_size,
                              hipStream_t stream)
{
    const float* x = (const float*)d_in[0];
    const float* W = (const float*)d_in[1];
    const float* b = (const float*)d_in[2];
    float* out = (float*)d_out;

    const size_t nx = (size_t)M_TOT * K_DIM;
    const size_t nw = (size_t)K_DIM * K_DIM;
    const size_t need = (nx + nw) * sizeof(unsigned short);
    if (ws_size < need) {
        fallback_fused<<<M_TOT, 256, 0, stream>>>(x, W, b, out);
        return;
    }
    unsigned short* xb = (unsigned short*)d_ws;
    unsigned short* wb = xb + nx;
    cvt_f32_bf16_2<<<2048, 256, 0, stream>>>((const float4*)x, (u16x4*)xb, (int)(nx / 4),
                                             (const float4*)W, (u16x4*)wb, (int)(nw / 4));
    gemm_rope<<<(M_TOT / 256) * (N_HALF / 128), 512, 0, stream>>>(xb, wb, b, out);
}